// Round 1
// baseline (766.186 us; speedup 1.0000x reference)
//
#include <hip/hip_runtime.h>
#include <hip/hip_bf16.h>
#include <stdint.h>
#include <math.h>

#define SEQ 2048
#define NTOK 8192        // B*S
#define EMB 1024
#define NH 16
#define HD 64
#define FFD 4096

using us = unsigned short;
using b8 = __attribute__((ext_vector_type(8))) __bf16;
using f4 = __attribute__((ext_vector_type(4))) float;

__device__ __forceinline__ us f2b(float f) {
  union { float f; uint32_t u; } v; v.f = f;
  uint32_t u = v.u;
  return (us)((u + 0x7fffu + ((u >> 16) & 1u)) >> 16);  // RNE
}

__device__ __forceinline__ void async16(void* lds, const void* g) {
  __builtin_amdgcn_global_load_lds(
      (__attribute__((address_space(1))) void*)(uintptr_t)g,
      (__attribute__((address_space(3))) void*)(uintptr_t)lds, 16, 0, 0);
}

// ---------------- transpose + cast: in [R][C] f32 -> out [C][R] bf16 ----------------
__global__ __launch_bounds__(256)
void transpose_cast(const float* __restrict__ in, us* __restrict__ out, int R, int C) {
  __shared__ float tile[32][33];
  const int bc = blockIdx.x * 32, br = blockIdx.y * 32;
  const int tx = threadIdx.x & 31, ty = threadIdx.x >> 5;
#pragma unroll
  for (int i = 0; i < 32; i += 8)
    tile[ty + i][tx] = in[(size_t)(br + ty + i) * C + bc + tx];
  __syncthreads();
#pragma unroll
  for (int i = 0; i < 32; i += 8)
    out[(size_t)(bc + ty + i) * R + br + tx] = f2b(tile[tx][ty + i]);
}

// ---------------- pack bq|bk|bv into one [3072] ----------------
__global__ void pack_bias(const float* __restrict__ bq, const float* __restrict__ bk,
                          const float* __restrict__ bv, float* __restrict__ o) {
  int i = blockIdx.x * 256 + threadIdx.x;
  o[i] = (i < 1024) ? bq[i] : (i < 2048 ? bk[i - 1024] : bv[i - 2048]);
}

// ---------------- LayerNorm: fp32 in -> bf16 out, one block per token ----------------
__global__ __launch_bounds__(256)
void ln_kernel(const float* __restrict__ x, const float* __restrict__ g,
               const float* __restrict__ be, us* __restrict__ out) {
  __shared__ float red[8];
  const int row = blockIdx.x, t = threadIdx.x;
  const float4 v = ((const float4*)(x + (size_t)row * EMB))[t];
  float s = v.x + v.y + v.z + v.w;
  float s2 = v.x * v.x + v.y * v.y + v.z * v.z + v.w * v.w;
#pragma unroll
  for (int o = 32; o; o >>= 1) { s += __shfl_down(s, o, 64); s2 += __shfl_down(s2, o, 64); }
  if ((t & 63) == 0) { red[(t >> 6) * 2] = s; red[(t >> 6) * 2 + 1] = s2; }
  __syncthreads();
  const float ts = red[0] + red[2] + red[4] + red[6];
  const float ts2 = red[1] + red[3] + red[5] + red[7];
  const float mu = ts * (1.f / 1024.f);
  const float rs = rsqrtf(ts2 * (1.f / 1024.f) - mu * mu + 1e-5f);
  const float4 gv = ((const float4*)g)[t];
  const float4 bv = ((const float4*)be)[t];
  ushort4 o4;
  o4.x = f2b((v.x - mu) * rs * gv.x + bv.x);
  o4.y = f2b((v.y - mu) * rs * gv.y + bv.y);
  o4.z = f2b((v.z - mu) * rs * gv.z + bv.z);
  o4.w = f2b((v.w - mu) * rs * gv.w + bv.w);
  ((ushort4*)(out + (size_t)row * EMB))[t] = o4;
}

// ---------------- GEMM: C[M][N] = epilogue(A[M][K] @ Bt[N][K]^T + bias) ----------------
// 128x128 tile, BK=32, 4 waves (2x2), 16x16x32 bf16 MFMA, global_load_lds staging.
__global__ __launch_bounds__(256, 2)
void gemm_bt(const us* __restrict__ A, const us* __restrict__ Bt,
             const float* __restrict__ bias, const float* __restrict__ resid,
             float* __restrict__ outF, us* __restrict__ outB,
             int M, int N, int K, int gelu) {
  __shared__ us As[128 * 32];
  __shared__ us Bs[128 * 32];
  const int tid = threadIdx.x;
  const int wave = tid >> 6, lane = tid & 63;
  const int wm = wave & 1, wn = wave >> 1;
  const int quad = lane >> 4, l15 = lane & 15;
  const int row0 = blockIdx.x * 128, col0 = blockIdx.y * 128;

  const f4 zf = {0.f, 0.f, 0.f, 0.f};
  f4 acc[4][4];
#pragma unroll
  for (int i = 0; i < 4; i++)
#pragma unroll
    for (int j = 0; j < 4; j++) acc[i][j] = zf;

  const us* Ap = A + (size_t)(row0 + wave * 32 + (lane >> 2)) * K + (lane & 3) * 8;
  const us* Bp = Bt + (size_t)(col0 + wave * 32 + (lane >> 2)) * K + (lane & 3) * 8;
  us* as0 = &As[(wave * 32) * 32];
  us* as1 = &As[(wave * 32 + 16) * 32];
  us* bs0 = &Bs[(wave * 32) * 32];
  us* bs1 = &Bs[(wave * 32 + 16) * 32];
  const size_t rstep = (size_t)16 * K;

  for (int k0 = 0; k0 < K; k0 += 32) {
    async16(as0, Ap + k0);
    async16(as1, Ap + rstep + k0);
    async16(bs0, Bp + k0);
    async16(bs1, Bp + rstep + k0);
    __syncthreads();   // drains vmcnt for global_load_lds
    b8 af[4], bf[4];
#pragma unroll
    for (int i = 0; i < 4; i++) {
      af[i] = *(const b8*)&As[(wm * 64 + i * 16 + l15) * 32 + quad * 8];
      bf[i] = *(const b8*)&Bs[(wn * 64 + i * 16 + l15) * 32 + quad * 8];
    }
#pragma unroll
    for (int i = 0; i < 4; i++)
#pragma unroll
      for (int j = 0; j < 4; j++)
        acc[i][j] = __builtin_amdgcn_mfma_f32_16x16x32_bf16(af[i], bf[j], acc[i][j], 0, 0, 0);
    __syncthreads();
  }

  float bcol[4];
#pragma unroll
  for (int j = 0; j < 4; j++) bcol[j] = bias[col0 + wn * 64 + j * 16 + l15];
#pragma unroll
  for (int i = 0; i < 4; i++)
#pragma unroll
    for (int j = 0; j < 4; j++)
#pragma unroll
      for (int r = 0; r < 4; r++) {
        const int grow = row0 + wm * 64 + i * 16 + quad * 4 + r;
        const int gcol = col0 + wn * 64 + j * 16 + l15;
        float v = acc[i][j][r] + bcol[j];
        if (resid) v += resid[(size_t)grow * N + gcol];
        if (gelu) v = 0.5f * v * (1.f + erff(v * 0.70710678118654752f));
        if (outF) outF[(size_t)grow * N + gcol] = v;
        if (outB) outB[(size_t)grow * N + gcol] = f2b(v);
      }
}

// ---------------- causal flash attention ----------------
// qkv: [NTOK][3072] bf16 (q|k|v per token). y: [NTOK][1024] bf16.
// block = (q-tile of 128 rows, one batch-head). 8 waves, 16 q-rows each.
__global__ __launch_bounds__(512, 1)
void attn(const us* __restrict__ qkv, us* __restrict__ y) {
  const int qt = blockIdx.x;
  const int bh = blockIdx.y;
  const int bb = bh >> 4, h = bh & 15;
  const int tid = threadIdx.x;
  const int wave = tid >> 6, lane = tid & 63;
  const int quad = lane >> 4, l15 = lane & 15;

  __shared__ us Ks[128 * 64];    // [key][d]
  __shared__ us Vt[64 * 128];    // [d][key], XOR-swizzled key-chunks
  __shared__ us Ps[128 * 128];   // [q][key], XOR-swizzled key-chunks (per-wave private rows)

  const size_t base = (size_t)bb * SEQ * 3072;
  const int q0 = qt * 128;

  // Q fragments (A-layout) straight from global; rows are wave-private.
  const us* qp = qkv + base + (size_t)(q0 + wave * 16 + l15) * 3072 + h * 64 + quad * 8;
  const b8 aq0 = *(const b8*)qp;
  const b8 aq1 = *(const b8*)(qp + 32);

  const f4 zf = {0.f, 0.f, 0.f, 0.f};
  f4 o[4];
  float mrow[4], lrow[4];
#pragma unroll
  for (int j = 0; j < 4; j++) { o[j] = zf; mrow[j] = -3.0e38f; lrow[j] = 0.f; }

  for (int kt = 0; kt <= qt; kt++) {
    const int k0 = kt * 128;
    {
      const int r = tid >> 3, c8 = (tid & 7) * 8;
      const us* ks = qkv + base + (size_t)(k0 + r) * 3072 + 1024 + h * 64 + c8;
      *(float4*)&Ks[r * 64 + c8] = *(const float4*)ks;
      *(float4*)&Ks[(r + 64) * 64 + c8] = *(const float4*)(ks + (size_t)64 * 3072);
      const us* vs = qkv + base + (size_t)(k0 + r) * 3072 + 2048 + h * 64 + c8;
      union { float4 f; us u[8]; } v0, v1;
      v0.f = *(const float4*)vs;
      v1.f = *(const float4*)(vs + (size_t)64 * 3072);
#pragma unroll
      for (int j = 0; j < 8; j++) {
        const int d = c8 + j;
        Vt[d * 128 + (((r >> 3) ^ (d & 7)) * 8) + (r & 7)] = v0.u[j];
        Vt[d * 128 + ((((r + 64) >> 3) ^ (d & 7)) * 8) + ((r + 64) & 7)] = v1.u[j];
      }
    }
    __syncthreads();

    // S = Q K^T  (each wave: its 16 q-rows x 128 keys)
    float sv[8][4];
#pragma unroll
    for (int kj = 0; kj < 8; kj++) {
      f4 s = zf;
      const b8 bk0 = *(const b8*)&Ks[(kj * 16 + l15) * 64 + quad * 8];
      const b8 bk1 = *(const b8*)&Ks[(kj * 16 + l15) * 64 + 32 + quad * 8];
      s = __builtin_amdgcn_mfma_f32_16x16x32_bf16(aq0, bk0, s, 0, 0, 0);
      s = __builtin_amdgcn_mfma_f32_16x16x32_bf16(aq1, bk1, s, 0, 0, 0);
#pragma unroll
      for (int r = 0; r < 4; r++) sv[kj][r] = s[r] * 0.125f;
    }
    if (kt == qt) {
#pragma unroll
      for (int kj = 0; kj < 8; kj++)
#pragma unroll
        for (int r = 0; r < 4; r++)
          if (kj * 16 + l15 > wave * 16 + quad * 4 + r) sv[kj][r] = -1e30f;
    }

    // online softmax (row lives in the 16 lanes of this quad-group)
#pragma unroll
    for (int r = 0; r < 4; r++) {
      float mx = sv[0][r];
#pragma unroll
      for (int kj = 1; kj < 8; kj++) mx = fmaxf(mx, sv[kj][r]);
#pragma unroll
      for (int d = 1; d < 16; d <<= 1) mx = fmaxf(mx, __shfl_xor(mx, d, 64));
      const float mnew = fmaxf(mrow[r], mx);
      const float alpha = __expf(mrow[r] - mnew);
      mrow[r] = mnew;
      const int prow = wave * 16 + quad * 4 + r;
      float rs = 0.f;
#pragma unroll
      for (int kj = 0; kj < 8; kj++) {
        const float p = __expf(sv[kj][r] - mnew);
        rs += p;
        const int key = kj * 16 + l15;
        Ps[prow * 128 + (((key >> 3) ^ (prow & 7)) * 8) + (key & 7)] = f2b(p);
      }
#pragma unroll
      for (int d = 1; d < 16; d <<= 1) rs += __shfl_xor(rs, d, 64);
      lrow[r] = lrow[r] * alpha + rs;
#pragma unroll
      for (int dj = 0; dj < 4; dj++) o[dj][r] *= alpha;
    }
    // Ps rows are wave-private: no barrier needed between write and A-layout read.

    // O += P V
#pragma unroll
    for (int kc = 0; kc < 4; kc++) {
      const int prow2 = wave * 16 + l15;
      const b8 pa = *(const b8*)&Ps[prow2 * 128 + (((kc * 4 + quad) ^ (prow2 & 7)) * 8)];
#pragma unroll
      for (int dj = 0; dj < 4; dj++) {
        const int d = dj * 16 + l15;
        const b8 vb = *(const b8*)&Vt[d * 128 + (((kc * 4 + quad) ^ (d & 7)) * 8)];
        o[dj] = __builtin_amdgcn_mfma_f32_16x16x32_bf16(pa, vb, o[dj], 0, 0, 0);
      }
    }
    __syncthreads();  // before next tile overwrites Ks/Vt
  }

#pragma unroll
  for (int dj = 0; dj < 4; dj++)
#pragma unroll
    for (int r = 0; r < 4; r++) {
      const int gq = q0 + wave * 16 + quad * 4 + r;
      const int col = h * 64 + dj * 16 + l15;
      y[(size_t)(bb * SEQ + gq) * EMB + col] = f2b(o[dj][r] / lrow[r]);
    }
}

extern "C" void kernel_launch(void* const* d_in, const int* in_sizes, int n_in,
                              void* d_out, int out_size, void* d_ws, size_t ws_size,
                              hipStream_t stream) {
  const float* x = (const float*)d_in[0];
  const float* Wq = (const float*)d_in[1];
  const float* bq = (const float*)d_in[2];
  const float* Wk = (const float*)d_in[3];
  const float* bk = (const float*)d_in[4];
  const float* Wv = (const float*)d_in[5];
  const float* bv = (const float*)d_in[6];
  const float* Wo = (const float*)d_in[7];
  const float* bo = (const float*)d_in[8];
  const float* g1 = (const float*)d_in[9];
  const float* be1 = (const float*)d_in[10];
  const float* g2 = (const float*)d_in[11];
  const float* be2 = (const float*)d_in[12];
  const float* W1 = (const float*)d_in[13];
  const float* b1 = (const float*)d_in[14];
  const float* W2 = (const float*)d_in[15];
  const float* b2 = (const float*)d_in[16];
  float* out = (float*)d_out;

  char* ws = (char*)d_ws;
  const size_t MB = 1024ull * 1024ull;
  us* WqkvT = (us*)(ws + 0);          // [3072][1024] bf16
  us* WoT   = (us*)(ws + 6 * MB);     // [1024][1024]
  us* W1T   = (us*)(ws + 8 * MB);     // [4096][1024]
  us* W2T   = (us*)(ws + 16 * MB);    // [1024][4096]
  us* hbuf  = (us*)(ws + 24 * MB);    // [8192][1024] bf16 (LN1 out)
  us* qkvb  = (us*)(ws + 40 * MB);    // [8192][3072] bf16
  us* ybuf  = (us*)(ws + 88 * MB);    // [8192][1024] bf16
  float* x1 = (float*)(ws + 104 * MB);// [8192][1024] f32
  us* h2    = (us*)(ws + 136 * MB);   // [8192][1024] bf16
  us* ff1   = (us*)(ws + 24 * MB);    // [8192][4096] bf16 (reuses h/qkv region)
  float* bqkv = (float*)(ws + 152 * MB); // [3072] f32

  transpose_cast<<<dim3(32, 32), 256, 0, stream>>>(Wq, WqkvT, 1024, 1024);
  transpose_cast<<<dim3(32, 32), 256, 0, stream>>>(Wk, WqkvT + 1024 * 1024, 1024, 1024);
  transpose_cast<<<dim3(32, 32), 256, 0, stream>>>(Wv, WqkvT + 2 * 1024 * 1024, 1024, 1024);
  transpose_cast<<<dim3(32, 32), 256, 0, stream>>>(Wo, WoT, 1024, 1024);
  transpose_cast<<<dim3(128, 32), 256, 0, stream>>>(W1, W1T, 1024, 4096);
  transpose_cast<<<dim3(32, 128), 256, 0, stream>>>(W2, W2T, 4096, 1024);
  pack_bias<<<12, 256, 0, stream>>>(bq, bk, bv, bqkv);

  ln_kernel<<<NTOK, 256, 0, stream>>>(x, g1, be1, hbuf);
  gemm_bt<<<dim3(64, 24), 256, 0, stream>>>(hbuf, WqkvT, bqkv, nullptr, nullptr, qkvb,
                                            NTOK, 3072, 1024, 0);
  attn<<<dim3(16, 64), 512, 0, stream>>>(qkvb, ybuf);
  gemm_bt<<<dim3(64, 8), 256, 0, stream>>>(ybuf, WoT, bo, x, x1, nullptr,
                                           NTOK, 1024, 1024, 0);
  ln_kernel<<<NTOK, 256, 0, stream>>>(x1, g2, be2, h2);
  gemm_bt<<<dim3(64, 32), 256, 0, stream>>>(h2, W1T, b1, nullptr, nullptr, ff1,
                                            NTOK, 4096, 1024, 1);
  gemm_bt<<<dim3(64, 8), 256, 0, stream>>>(ff1, W2T, b2, x1, out, nullptr,
                                           NTOK, 1024, 4096, 0);
}

// Round 2
// 622.727 us; speedup vs baseline: 1.2304x; 1.2304x over previous
//
#include <hip/hip_runtime.h>
#include <hip/hip_bf16.h>
#include <stdint.h>
#include <math.h>

#define SEQ 2048
#define NTOK 8192        // B*S
#define EMB 1024
#define NH 16
#define HD 64
#define FFD 4096

using us = unsigned short;
using b8 = __attribute__((ext_vector_type(8))) __bf16;
using f4 = __attribute__((ext_vector_type(4))) float;

__device__ __forceinline__ us f2b(float f) {
  union { float f; uint32_t u; } v; v.f = f;
  uint32_t u = v.u;
  return (us)((u + 0x7fffu + ((u >> 16) & 1u)) >> 16);  // RNE
}

// pack two fp32 -> bf16x2 (round-half-up; P in [0,1], bias negligible)
__device__ __forceinline__ uint32_t pkbf(float a, float b) {
  union { float f; uint32_t u; } x, y; x.f = a; y.f = b;
  return ((x.u + 0x8000u) >> 16) | ((y.u + 0x8000u) & 0xFFFF0000u);
}

__device__ __forceinline__ void async16(void* lds, const void* g) {
  __builtin_amdgcn_global_load_lds(
      (__attribute__((address_space(1))) void*)(uintptr_t)g,
      (__attribute__((address_space(3))) void*)(uintptr_t)lds, 16, 0, 0);
}

// ---------------- transpose + cast: in [R][C] f32 -> out [C][R] bf16 ----------------
__global__ __launch_bounds__(256)
void transpose_cast(const float* __restrict__ in, us* __restrict__ out, int R, int C) {
  __shared__ float tile[32][33];
  const int bc = blockIdx.x * 32, br = blockIdx.y * 32;
  const int tx = threadIdx.x & 31, ty = threadIdx.x >> 5;
#pragma unroll
  for (int i = 0; i < 32; i += 8)
    tile[ty + i][tx] = in[(size_t)(br + ty + i) * C + bc + tx];
  __syncthreads();
#pragma unroll
  for (int i = 0; i < 32; i += 8)
    out[(size_t)(bc + ty + i) * R + br + tx] = f2b(tile[tx][ty + i]);
}

// ---------------- pack bq|bk|bv into one [3072] ----------------
__global__ void pack_bias(const float* __restrict__ bq, const float* __restrict__ bk,
                          const float* __restrict__ bv, float* __restrict__ o) {
  int i = blockIdx.x * 256 + threadIdx.x;
  o[i] = (i < 1024) ? bq[i] : (i < 2048 ? bk[i - 1024] : bv[i - 2048]);
}

// ---------------- LayerNorm: fp32 in -> bf16 out, one block per token ----------------
__global__ __launch_bounds__(256)
void ln_kernel(const float* __restrict__ x, const float* __restrict__ g,
               const float* __restrict__ be, us* __restrict__ out) {
  __shared__ float red[8];
  const int row = blockIdx.x, t = threadIdx.x;
  const float4 v = ((const float4*)(x + (size_t)row * EMB))[t];
  float s = v.x + v.y + v.z + v.w;
  float s2 = v.x * v.x + v.y * v.y + v.z * v.z + v.w * v.w;
#pragma unroll
  for (int o = 32; o; o >>= 1) { s += __shfl_down(s, o, 64); s2 += __shfl_down(s2, o, 64); }
  if ((t & 63) == 0) { red[(t >> 6) * 2] = s; red[(t >> 6) * 2 + 1] = s2; }
  __syncthreads();
  const float ts = red[0] + red[2] + red[4] + red[6];
  const float ts2 = red[1] + red[3] + red[5] + red[7];
  const float mu = ts * (1.f / 1024.f);
  const float rs = rsqrtf(ts2 * (1.f / 1024.f) - mu * mu + 1e-5f);
  const float4 gv = ((const float4*)g)[t];
  const float4 bv = ((const float4*)be)[t];
  ushort4 o4;
  o4.x = f2b((v.x - mu) * rs * gv.x + bv.x);
  o4.y = f2b((v.y - mu) * rs * gv.y + bv.y);
  o4.z = f2b((v.z - mu) * rs * gv.z + bv.z);
  o4.w = f2b((v.w - mu) * rs * gv.w + bv.w);
  ((ushort4*)(out + (size_t)row * EMB))[t] = o4;
}

// ---------------- GEMM: C[M][N] = epilogue(A[M][K] @ Bt[N][K]^T + bias) ----------------
// 128x128 tile, BK=32, 4 waves (2x2), 16x16x32 bf16 MFMA, global_load_lds staging.
__global__ __launch_bounds__(256, 2)
void gemm_bt(const us* __restrict__ A, const us* __restrict__ Bt,
             const float* __restrict__ bias, const float* __restrict__ resid,
             float* __restrict__ outF, us* __restrict__ outB,
             int M, int N, int K, int gelu) {
  __shared__ us As[128 * 32];
  __shared__ us Bs[128 * 32];
  const int tid = threadIdx.x;
  const int wave = tid >> 6, lane = tid & 63;
  const int wm = wave & 1, wn = wave >> 1;
  const int quad = lane >> 4, l15 = lane & 15;
  const int row0 = blockIdx.x * 128, col0 = blockIdx.y * 128;

  const f4 zf = {0.f, 0.f, 0.f, 0.f};
  f4 acc[4][4];
#pragma unroll
  for (int i = 0; i < 4; i++)
#pragma unroll
    for (int j = 0; j < 4; j++) acc[i][j] = zf;

  const us* Ap = A + (size_t)(row0 + wave * 32 + (lane >> 2)) * K + (lane & 3) * 8;
  const us* Bp = Bt + (size_t)(col0 + wave * 32 + (lane >> 2)) * K + (lane & 3) * 8;
  us* as0 = &As[(wave * 32) * 32];
  us* as1 = &As[(wave * 32 + 16) * 32];
  us* bs0 = &Bs[(wave * 32) * 32];
  us* bs1 = &Bs[(wave * 32 + 16) * 32];
  const size_t rstep = (size_t)16 * K;

  for (int k0 = 0; k0 < K; k0 += 32) {
    async16(as0, Ap + k0);
    async16(as1, Ap + rstep + k0);
    async16(bs0, Bp + k0);
    async16(bs1, Bp + rstep + k0);
    __syncthreads();   // drains vmcnt for global_load_lds
    b8 af[4], bf[4];
#pragma unroll
    for (int i = 0; i < 4; i++) {
      af[i] = *(const b8*)&As[(wm * 64 + i * 16 + l15) * 32 + quad * 8];
      bf[i] = *(const b8*)&Bs[(wn * 64 + i * 16 + l15) * 32 + quad * 8];
    }
#pragma unroll
    for (int i = 0; i < 4; i++)
#pragma unroll
      for (int j = 0; j < 4; j++)
        acc[i][j] = __builtin_amdgcn_mfma_f32_16x16x32_bf16(af[i], bf[j], acc[i][j], 0, 0, 0);
    __syncthreads();
  }

  float bcol[4];
#pragma unroll
  for (int j = 0; j < 4; j++) bcol[j] = bias[col0 + wn * 64 + j * 16 + l15];
#pragma unroll
  for (int i = 0; i < 4; i++)
#pragma unroll
    for (int j = 0; j < 4; j++)
#pragma unroll
      for (int r = 0; r < 4; r++) {
        const int grow = row0 + wm * 64 + i * 16 + quad * 4 + r;
        const int gcol = col0 + wn * 64 + j * 16 + l15;
        float v = acc[i][j][r] + bcol[j];
        if (resid) v += resid[(size_t)grow * N + gcol];
        if (gelu) v = 0.5f * v * (1.f + erff(v * 0.70710678118654752f));
        if (outF) outF[(size_t)grow * N + gcol] = v;
        if (outB) outB[(size_t)grow * N + gcol] = f2b(v);
      }
}

// ---------------- causal flash attention, operand-swapped ----------------
// qkv: [NTOK][3072] bf16 (q|k|v). y: [NTOK][1024] bf16.
// Computes S^T = K·Q^T so P stays in registers in A-operand layout for O = P·V.
// 512 threads = 8 waves, each wave owns 16 q rows of a 128-row q-tile.
__global__ __launch_bounds__(512, 4)
void attn(const us* __restrict__ qkv, us* __restrict__ y) {
  // magic-square qt mapping: each CU-coset of blocks gets equal total work
  static const signed char QTM[16] = {15,14,13,12, 10,11,8,9, 5,4,7,6, 0,1,2,3};
  const int bx = blockIdx.x;
  const int bh = bx & 63;
  const int qt = QTM[(bx >> 6) & 15];
  const int bb = bh >> 4, h = bh & 15;
  const int tid = threadIdx.x;
  const int wave = tid >> 6, lane = tid & 63;
  const int quad = lane >> 4, l15 = lane & 15;

  __shared__ us Ks[128 * 64];     // [key][d]
  __shared__ us Vt2[64 * 264];    // [d][slot]; slot = 32c+8q+j for key=16c+4q+j; pads zeroed

  const size_t base = (size_t)bb * SEQ * 3072;
  const int q0 = qt * 128;

  // Q as B-operand fragments (q = l15 within wave's 16-row group)
  const us* qp = qkv + base + (size_t)(q0 + wave * 16 + l15) * 3072 + h * 64 + quad * 8;
  const b8 bq0 = *(const b8*)qp;
  const b8 bq1 = *(const b8*)(qp + 32);

  const f4 zf = {0.f, 0.f, 0.f, 0.f};
  f4 o[4];                       // O[q=quad*4+r][d=dg*16+l15]
#pragma unroll
  for (int j = 0; j < 4; j++) o[j] = zf;
  float mrow = -3.0e38f, lrow = 0.f;   // softmax state for row q=l15 (replicated per quad)

  // staging indices
  const int sr = tid >> 3;            // 0..63 -> key pair (2sr, 2sr+1)
  const int sc8 = (tid & 7) * 8;      // d base
  const int kk = 2 * sr;
  const int slot0 = 32 * (kk >> 4) + 8 * ((kk >> 2) & 3) + (kk & 3);
  us* ksdst0 = &Ks[(wave * 8 + (lane >> 3)) * 64 + (lane & 7) * 8];
  us* ksdst1 = ksdst0 + 64 * 64;
  const us* kgbase = qkv + base + (size_t)(wave * 8 + (lane >> 3)) * 3072 + 1024 + h * 64 + (lane & 7) * 8;
  const us* vgbase = qkv + base + (size_t)kk * 3072 + 2048 + h * 64 + sc8;

  const float sm_scale = 0.125f * 1.44269504088896340736f;  // 1/sqrt(64) * log2(e)
  const int q_in = wave * 16 + l15;

  for (int kt = 0; kt <= qt; kt++) {
    const size_t koff = (size_t)(kt * 128) * 3072;
    // K stage: direct global->LDS, rows contiguous per wave
    async16(ksdst0, kgbase + koff);
    async16(ksdst1, kgbase + koff + (size_t)64 * 3072);
    // V stage: transposed into slot layout, paired b32 writes
    {
      union { float4 f; us u[8]; } v0, v1;
      v0.f = *(const float4*)(vgbase + koff);
      v1.f = *(const float4*)(vgbase + koff + 3072);
#pragma unroll
      for (int j = 0; j < 8; j++)
        *(uint32_t*)&Vt2[(sc8 + j) * 264 + slot0] =
            (uint32_t)v0.u[j] | ((uint32_t)v1.u[j] << 16);
      if ((sr & 1) == 0) {
        const int ps = slot0 + 4;   // pad run for this (c,q): slots +4..7
#pragma unroll
        for (int j = 0; j < 8; j++)
          *(uint64_t*)&Vt2[(sc8 + j) * 264 + ps] = 0ull;
      }
    }
    __syncthreads();

    // S^T = K·Q^T : chunk c holds S^T[key=16c+4*quad+r][q=l15]
    f4 sacc[8];
#pragma unroll
    for (int c = 0; c < 8; c++) {
      f4 s = zf;
      const b8 ak0 = *(const b8*)&Ks[(c * 16 + l15) * 64 + quad * 8];
      const b8 ak1 = *(const b8*)&Ks[(c * 16 + l15) * 64 + 32 + quad * 8];
      s = __builtin_amdgcn_mfma_f32_16x16x32_bf16(ak0, bq0, s, 0, 0, 0);
      s = __builtin_amdgcn_mfma_f32_16x16x32_bf16(ak1, bq1, s, 0, 0, 0);
      sacc[c] = s;
    }

    // scale to log2 space + causal mask
#pragma unroll
    for (int c = 0; c < 8; c++)
#pragma unroll
      for (int r = 0; r < 4; r++) {
        float v = sacc[c][r] * sm_scale;
        if (kt == qt && (c * 16 + quad * 4 + r) > q_in) v = -3.0e38f;
        sacc[c][r] = v;
      }

    // row max: 32 in-lane values + 2 cross-quad shuffles
    float mx = sacc[0][0];
#pragma unroll
    for (int c = 0; c < 8; c++)
#pragma unroll
      for (int r = 0; r < 4; r++) mx = fmaxf(mx, sacc[c][r]);
    mx = fmaxf(mx, __shfl_xor(mx, 16, 64));
    mx = fmaxf(mx, __shfl_xor(mx, 32, 64));
    const float mnew = fmaxf(mrow, mx);
    const float alpha = __builtin_amdgcn_exp2f(mrow - mnew);
    mrow = mnew;

    // P = exp2(S' - m'), packed straight into A-fragment halves
    float rs = 0.f;
    uint32_t pf[16];
#pragma unroll
    for (int c = 0; c < 8; c++) {
      const float p0 = __builtin_amdgcn_exp2f(sacc[c][0] - mnew);
      const float p1 = __builtin_amdgcn_exp2f(sacc[c][1] - mnew);
      const float p2 = __builtin_amdgcn_exp2f(sacc[c][2] - mnew);
      const float p3 = __builtin_amdgcn_exp2f(sacc[c][3] - mnew);
      rs += (p0 + p1) + (p2 + p3);
      pf[c * 2] = pkbf(p0, p1);
      pf[c * 2 + 1] = pkbf(p2, p3);
    }
    rs += __shfl_xor(rs, 16, 64);
    rs += __shfl_xor(rs, 32, 64);
    lrow = lrow * alpha + rs;

    // rescale O rows (row q' = quad*4+r needs alpha from lane l15=q')
#pragma unroll
    for (int r = 0; r < 4; r++) {
      const float ar = __shfl(alpha, quad * 4 + r, 64);
#pragma unroll
      for (int dg = 0; dg < 4; dg++) o[dg][r] *= ar;
    }

    // O += P·V  (zero-padded 16-key chunks; V slots for j>=4 are zeroed)
#pragma unroll
    for (int c = 0; c < 8; c++) {
      union { uint32_t w[4]; b8 v; } af;
      af.w[0] = pf[c * 2]; af.w[1] = pf[c * 2 + 1]; af.w[2] = 0u; af.w[3] = 0u;
#pragma unroll
      for (int dg = 0; dg < 4; dg++) {
        const b8 vb = *(const b8*)&Vt2[(dg * 16 + l15) * 264 + c * 32 + quad * 8];
        o[dg] = __builtin_amdgcn_mfma_f32_16x16x32_bf16(af.v, vb, o[dg], 0, 0, 0);
      }
    }
    __syncthreads();   // before next tile overwrites Ks/Vt2
  }

  float lr[4];
#pragma unroll
  for (int r = 0; r < 4; r++) lr[r] = __shfl(lrow, quad * 4 + r, 64);
#pragma unroll
  for (int dg = 0; dg < 4; dg++)
#pragma unroll
    for (int r = 0; r < 4; r++) {
      const int gq = q0 + wave * 16 + quad * 4 + r;
      y[(size_t)(bb * SEQ + gq) * EMB + h * 64 + dg * 16 + l15] = f2b(o[dg][r] / lr[r]);
    }
}

extern "C" void kernel_launch(void* const* d_in, const int* in_sizes, int n_in,
                              void* d_out, int out_size, void* d_ws, size_t ws_size,
                              hipStream_t stream) {
  const float* x = (const float*)d_in[0];
  const float* Wq = (const float*)d_in[1];
  const float* bq = (const float*)d_in[2];
  const float* Wk = (const float*)d_in[3];
  const float* bk = (const float*)d_in[4];
  const float* Wv = (const float*)d_in[5];
  const float* bv = (const float*)d_in[6];
  const float* Wo = (const float*)d_in[7];
  const float* bo = (const float*)d_in[8];
  const float* g1 = (const float*)d_in[9];
  const float* be1 = (const float*)d_in[10];
  const float* g2 = (const float*)d_in[11];
  const float* be2 = (const float*)d_in[12];
  const float* W1 = (const float*)d_in[13];
  const float* b1 = (const float*)d_in[14];
  const float* W2 = (const float*)d_in[15];
  const float* b2 = (const float*)d_in[16];
  float* out = (float*)d_out;

  char* ws = (char*)d_ws;
  const size_t MB = 1024ull * 1024ull;
  us* WqkvT = (us*)(ws + 0);          // [3072][1024] bf16
  us* WoT   = (us*)(ws + 6 * MB);     // [1024][1024]
  us* W1T   = (us*)(ws + 8 * MB);     // [4096][1024]
  us* W2T   = (us*)(ws + 16 * MB);    // [1024][4096]
  us* hbuf  = (us*)(ws + 24 * MB);    // [8192][1024] bf16 (LN1 out)
  us* qkvb  = (us*)(ws + 40 * MB);    // [8192][3072] bf16
  us* ybuf  = (us*)(ws + 88 * MB);    // [8192][1024] bf16
  float* x1 = (float*)(ws + 104 * MB);// [8192][1024] f32
  us* h2    = (us*)(ws + 136 * MB);   // [8192][1024] bf16
  us* ff1   = (us*)(ws + 24 * MB);    // [8192][4096] bf16 (reuses h/qkv region)
  float* bqkv = (float*)(ws + 152 * MB); // [3072] f32

  transpose_cast<<<dim3(32, 32), 256, 0, stream>>>(Wq, WqkvT, 1024, 1024);
  transpose_cast<<<dim3(32, 32), 256, 0, stream>>>(Wk, WqkvT + 1024 * 1024, 1024, 1024);
  transpose_cast<<<dim3(32, 32), 256, 0, stream>>>(Wv, WqkvT + 2 * 1024 * 1024, 1024, 1024);
  transpose_cast<<<dim3(32, 32), 256, 0, stream>>>(Wo, WoT, 1024, 1024);
  transpose_cast<<<dim3(128, 32), 256, 0, stream>>>(W1, W1T, 1024, 4096);
  transpose_cast<<<dim3(32, 128), 256, 0, stream>>>(W2, W2T, 4096, 1024);
  pack_bias<<<12, 256, 0, stream>>>(bq, bk, bv, bqkv);

  ln_kernel<<<NTOK, 256, 0, stream>>>(x, g1, be1, hbuf);
  gemm_bt<<<dim3(64, 24), 256, 0, stream>>>(hbuf, WqkvT, bqkv, nullptr, nullptr, qkvb,
                                            NTOK, 3072, 1024, 0);
  attn<<<1024, 512, 0, stream>>>(qkvb, ybuf);
  gemm_bt<<<dim3(64, 8), 256, 0, stream>>>(ybuf, WoT, bo, x, x1, nullptr,
                                           NTOK, 1024, 1024, 0);
  ln_kernel<<<NTOK, 256, 0, stream>>>(x1, g2, be2, h2);
  gemm_bt<<<dim3(64, 32), 256, 0, stream>>>(h2, W1T, b1, nullptr, nullptr, ff1,
                                            NTOK, 4096, 1024, 1);
  gemm_bt<<<dim3(64, 8), 256, 0, stream>>>(ff1, W2T, b2, x1, out, nullptr,
                                           NTOK, 1024, 4096, 0);
}

// Round 3
// 586.223 us; speedup vs baseline: 1.3070x; 1.0623x over previous
//
#include <hip/hip_runtime.h>
#include <hip/hip_bf16.h>
#include <stdint.h>
#include <math.h>

#define SEQ 2048
#define NTOK 8192        // B*S
#define EMB 1024
#define NH 16
#define HD 64
#define FFD 4096

using us = unsigned short;
using b8 = __attribute__((ext_vector_type(8))) __bf16;
using f4 = __attribute__((ext_vector_type(4))) float;

__device__ __forceinline__ us f2b(float f) {
  union { float f; uint32_t u; } v; v.f = f;
  uint32_t u = v.u;
  return (us)((u + 0x7fffu + ((u >> 16) & 1u)) >> 16);  // RNE
}

// pack two fp32 -> bf16x2 (round-half-up; P in [0,1], bias negligible)
__device__ __forceinline__ uint32_t pkbf(float a, float b) {
  union { float f; uint32_t u; } x, y; x.f = a; y.f = b;
  return ((x.u + 0x8000u) >> 16) | ((y.u + 0x8000u) & 0xFFFF0000u);
}

__device__ __forceinline__ void async16(void* lds, const void* g) {
  __builtin_amdgcn_global_load_lds(
      (__attribute__((address_space(1))) void*)(uintptr_t)g,
      (__attribute__((address_space(3))) void*)(uintptr_t)lds, 16, 0, 0);
}

// ---------------- transpose + cast: in [R][C] f32 -> out [C][R] bf16 ----------------
__global__ __launch_bounds__(256)
void transpose_cast(const float* __restrict__ in, us* __restrict__ out, int R, int C) {
  __shared__ float tile[32][33];
  const int bc = blockIdx.x * 32, br = blockIdx.y * 32;
  const int tx = threadIdx.x & 31, ty = threadIdx.x >> 5;
#pragma unroll
  for (int i = 0; i < 32; i += 8)
    tile[ty + i][tx] = in[(size_t)(br + ty + i) * C + bc + tx];
  __syncthreads();
#pragma unroll
  for (int i = 0; i < 32; i += 8)
    out[(size_t)(bc + ty + i) * R + br + tx] = f2b(tile[tx][ty + i]);
}

// ---------------- pack bq|bk|bv into one [3072] ----------------
__global__ void pack_bias(const float* __restrict__ bq, const float* __restrict__ bk,
                          const float* __restrict__ bv, float* __restrict__ o) {
  int i = blockIdx.x * 256 + threadIdx.x;
  o[i] = (i < 1024) ? bq[i] : (i < 2048 ? bk[i - 1024] : bv[i - 2048]);
}

// ---------------- LayerNorm: fp32 in -> bf16 out, one block per token ----------------
__global__ __launch_bounds__(256)
void ln_kernel(const float* __restrict__ x, const float* __restrict__ g,
               const float* __restrict__ be, us* __restrict__ out) {
  __shared__ float red[8];
  const int row = blockIdx.x, t = threadIdx.x;
  const float4 v = ((const float4*)(x + (size_t)row * EMB))[t];
  float s = v.x + v.y + v.z + v.w;
  float s2 = v.x * v.x + v.y * v.y + v.z * v.z + v.w * v.w;
#pragma unroll
  for (int o = 32; o; o >>= 1) { s += __shfl_down(s, o, 64); s2 += __shfl_down(s2, o, 64); }
  if ((t & 63) == 0) { red[(t >> 6) * 2] = s; red[(t >> 6) * 2 + 1] = s2; }
  __syncthreads();
  const float ts = red[0] + red[2] + red[4] + red[6];
  const float ts2 = red[1] + red[3] + red[5] + red[7];
  const float mu = ts * (1.f / 1024.f);
  const float rs = rsqrtf(ts2 * (1.f / 1024.f) - mu * mu + 1e-5f);
  const float4 gv = ((const float4*)g)[t];
  const float4 bv = ((const float4*)be)[t];
  ushort4 o4;
  o4.x = f2b((v.x - mu) * rs * gv.x + bv.x);
  o4.y = f2b((v.y - mu) * rs * gv.y + bv.y);
  o4.z = f2b((v.z - mu) * rs * gv.z + bv.z);
  o4.w = f2b((v.w - mu) * rs * gv.w + bv.w);
  ((ushort4*)(out + (size_t)row * EMB))[t] = o4;
}

// ---------------- GEMM: C[M][N] = epilogue(A[M][K] @ Bt[N][K]^T + bias) ----------------
// 128x128 tile, BK=32, 4 waves (2x2), 16x16x32 bf16 MFMA, global_load_lds staging.
__global__ __launch_bounds__(256, 2)
void gemm_bt(const us* __restrict__ A, const us* __restrict__ Bt,
             const float* __restrict__ bias, const float* __restrict__ resid,
             float* __restrict__ outF, us* __restrict__ outB,
             int M, int N, int K, int gelu) {
  __shared__ us As[128 * 32];
  __shared__ us Bs[128 * 32];
  const int tid = threadIdx.x;
  const int wave = tid >> 6, lane = tid & 63;
  const int wm = wave & 1, wn = wave >> 1;
  const int quad = lane >> 4, l15 = lane & 15;
  const int row0 = blockIdx.x * 128, col0 = blockIdx.y * 128;

  const f4 zf = {0.f, 0.f, 0.f, 0.f};
  f4 acc[4][4];
#pragma unroll
  for (int i = 0; i < 4; i++)
#pragma unroll
    for (int j = 0; j < 4; j++) acc[i][j] = zf;

  const us* Ap = A + (size_t)(row0 + wave * 32 + (lane >> 2)) * K + (lane & 3) * 8;
  const us* Bp = Bt + (size_t)(col0 + wave * 32 + (lane >> 2)) * K + (lane & 3) * 8;
  us* as0 = &As[(wave * 32) * 32];
  us* as1 = &As[(wave * 32 + 16) * 32];
  us* bs0 = &Bs[(wave * 32) * 32];
  us* bs1 = &Bs[(wave * 32 + 16) * 32];
  const size_t rstep = (size_t)16 * K;

  for (int k0 = 0; k0 < K; k0 += 32) {
    async16(as0, Ap + k0);
    async16(as1, Ap + rstep + k0);
    async16(bs0, Bp + k0);
    async16(bs1, Bp + rstep + k0);
    __syncthreads();   // drains vmcnt for global_load_lds
    b8 af[4], bf[4];
#pragma unroll
    for (int i = 0; i < 4; i++) {
      af[i] = *(const b8*)&As[(wm * 64 + i * 16 + l15) * 32 + quad * 8];
      bf[i] = *(const b8*)&Bs[(wn * 64 + i * 16 + l15) * 32 + quad * 8];
    }
#pragma unroll
    for (int i = 0; i < 4; i++)
#pragma unroll
      for (int j = 0; j < 4; j++)
        acc[i][j] = __builtin_amdgcn_mfma_f32_16x16x32_bf16(af[i], bf[j], acc[i][j], 0, 0, 0);
    __syncthreads();
  }

  float bcol[4];
#pragma unroll
  for (int j = 0; j < 4; j++) bcol[j] = bias[col0 + wn * 64 + j * 16 + l15];
#pragma unroll
  for (int i = 0; i < 4; i++)
#pragma unroll
    for (int j = 0; j < 4; j++)
#pragma unroll
      for (int r = 0; r < 4; r++) {
        const int grow = row0 + wm * 64 + i * 16 + quad * 4 + r;
        const int gcol = col0 + wn * 64 + j * 16 + l15;
        float v = acc[i][j][r] + bcol[j];
        if (resid) v += resid[(size_t)grow * N + gcol];
        if (gelu) v = 0.5f * v * (1.f + erff(v * 0.70710678118654752f));
        if (outF) outF[(size_t)grow * N + gcol] = v;
        if (outB) outB[(size_t)grow * N + gcol] = f2b(v);
      }
}

// ---------------- causal flash attention, operand-swapped, reg-blocked ----------------
// qkv: [NTOK][3072] bf16 (q|k|v). y: [NTOK][1024] bf16.
// S^T = K·Q^T (P stays in registers in A-layout for O = P·V).
// 256 threads = 4 waves; each wave owns 32 q-rows (two 16-q groups) of a 128-q tile.
// K in LDS with XOR column swizzle (conflict-free b128 reads, async-DMA staged).
// V^T in LDS stride 132 us, b64 reads + register zero-pad (conflict-free).
__global__ __launch_bounds__(256, 3)
void attn(const us* __restrict__ qkv, us* __restrict__ y) {
  // magic-square qt mapping: each CU-coset of blocks gets equal total work
  static const signed char QTM[16] = {15,14,13,12, 10,11,8,9, 5,4,7,6, 0,1,2,3};
  const int bx = blockIdx.x;
  const int bh = bx & 63;
  const int qt = QTM[(bx >> 6) & 15];
  const int bb = bh >> 4, h = bh & 15;
  const int tid = threadIdx.x;
  const int wave = tid >> 6, lane = tid & 63;
  const int quad = lane >> 4, l15 = lane & 15;

  __shared__ us Ks[128 * 64];   // phys us off = row*64 + ((col8 ^ (row&7))<<3)
  __shared__ us Vt[64 * 132];   // V^T[d][key], us off = d*132 + key

  const size_t base = (size_t)bb * SEQ * 3072;
  const int q0 = qt * 128;

  // Q B-fragments for two 16-q groups (rows wave*32 + qg*16 + l15)
  b8 bqf[2][2];
#pragma unroll
  for (int qg = 0; qg < 2; qg++) {
    const us* qp = qkv + base + (size_t)(q0 + wave * 32 + qg * 16 + l15) * 3072 + h * 64 + quad * 8;
    bqf[qg][0] = *(const b8*)qp;
    bqf[qg][1] = *(const b8*)(qp + 32);
  }

  const f4 zf = {0.f, 0.f, 0.f, 0.f};
  f4 o[2][4];                       // [qg][dg]: O[q=quad*4+r][d=dg*16+l15]
  float mrow[2], lrow[2];
#pragma unroll
  for (int qg = 0; qg < 2; qg++) {
    mrow[qg] = -3.0e38f; lrow[qg] = 0.f;
#pragma unroll
    for (int dg = 0; dg < 4; dg++) o[qg][dg] = zf;
  }

  // K staging: wave stages rows wave*32..+31 in 4 DMA ops of 8 rows.
  const int klr = lane >> 3, klc = lane & 7;
  const us* kgbase = qkv + base + (size_t)(wave * 32 + klr) * 3072 + 1024 + h * 64 + ((klc ^ klr) << 3);
  // V staging: thread handles key pair (2*lane, 2*lane+1), d-octets wave*8 and 32+wave*8.
  const us* vgbase = qkv + base + (size_t)(2 * lane) * 3072 + 2048 + h * 64 + wave * 8;

  const float sm_scale = 0.125f * 1.44269504088896340736f;  // 1/sqrt(64) * log2(e)

  for (int kt = 0; kt <= qt; kt++) {
    const size_t koff = (size_t)kt * 128 * 3072;
    // --- stage K (async DMA, XOR-swizzled source) ---
#pragma unroll
    for (int op = 0; op < 4; op++)
      async16(&Ks[(wave * 32 + op * 8) * 64], kgbase + koff + (size_t)op * 8 * 3072);
    // --- stage V^T (manual transpose, conflict-free packed writes) ---
    {
      union { float4 f; us u[8]; } v0, v1, v2, v3;
      v0.f = *(const float4*)(vgbase + koff);
      v1.f = *(const float4*)(vgbase + koff + 3072);
      v2.f = *(const float4*)(vgbase + koff + 32);
      v3.f = *(const float4*)(vgbase + koff + 3072 + 32);
#pragma unroll
      for (int j = 0; j < 8; j++) {
        *(uint32_t*)&Vt[(wave * 8 + j) * 132 + 2 * lane] =
            (uint32_t)v0.u[j] | ((uint32_t)v1.u[j] << 16);
        *(uint32_t*)&Vt[(32 + wave * 8 + j) * 132 + 2 * lane] =
            (uint32_t)v2.u[j] | ((uint32_t)v3.u[j] << 16);
      }
    }
    __syncthreads();

    // --- S^T = K·Q^T : sacc[qg][c] holds S^T[key=c*16+quad*4+r][q=l15] ---
    f4 sacc[2][8];
#pragma unroll
    for (int c = 0; c < 8; c++) {
      const int krow = (c * 16 + l15) * 64;
      const int sw = l15 & 7;
      const b8 ak0 = *(const b8*)&Ks[krow + ((quad ^ sw) << 3)];
      const b8 ak1 = *(const b8*)&Ks[krow + (((quad ^ 4) ^ sw) << 3)];
#pragma unroll
      for (int qg = 0; qg < 2; qg++) {
        f4 s = __builtin_amdgcn_mfma_f32_16x16x32_bf16(ak0, bqf[qg][0], zf, 0, 0, 0);
        sacc[qg][c] = __builtin_amdgcn_mfma_f32_16x16x32_bf16(ak1, bqf[qg][1], s, 0, 0, 0);
      }
    }

    // --- softmax per q-group; pack P into A-fragment halves ---
    uint32_t pf[2][16];
    float alpha[2];
#pragma unroll
    for (int qg = 0; qg < 2; qg++) {
      const int q_in = wave * 32 + qg * 16 + l15;
#pragma unroll
      for (int c = 0; c < 8; c++)
#pragma unroll
        for (int r = 0; r < 4; r++) {
          float v = sacc[qg][c][r] * sm_scale;
          if (kt == qt && (c * 16 + quad * 4 + r) > q_in) v = -3.0e38f;
          sacc[qg][c][r] = v;
        }
      float mx = sacc[qg][0][0];
#pragma unroll
      for (int c = 0; c < 8; c++)
#pragma unroll
        for (int r = 0; r < 4; r++) mx = fmaxf(mx, sacc[qg][c][r]);
      mx = fmaxf(mx, __shfl_xor(mx, 16, 64));
      mx = fmaxf(mx, __shfl_xor(mx, 32, 64));
      const float mnew = fmaxf(mrow[qg], mx);
      alpha[qg] = __builtin_amdgcn_exp2f(mrow[qg] - mnew);
      mrow[qg] = mnew;
      float rs = 0.f;
#pragma unroll
      for (int c = 0; c < 8; c++) {
        const float p0 = __builtin_amdgcn_exp2f(sacc[qg][c][0] - mnew);
        const float p1 = __builtin_amdgcn_exp2f(sacc[qg][c][1] - mnew);
        const float p2 = __builtin_amdgcn_exp2f(sacc[qg][c][2] - mnew);
        const float p3 = __builtin_amdgcn_exp2f(sacc[qg][c][3] - mnew);
        rs += (p0 + p1) + (p2 + p3);
        pf[qg][c * 2] = pkbf(p0, p1);
        pf[qg][c * 2 + 1] = pkbf(p2, p3);
      }
      rs += __shfl_xor(rs, 16, 64);
      rs += __shfl_xor(rs, 32, 64);
      lrow[qg] = lrow[qg] * alpha[qg] + rs;
      // rescale O rows (row q' = quad*4+r needs alpha from lane l15=q')
#pragma unroll
      for (int r = 0; r < 4; r++) {
        const float ar = __shfl(alpha[qg], quad * 4 + r, 64);
#pragma unroll
        for (int dg = 0; dg < 4; dg++) o[qg][dg][r] *= ar;
      }
    }

    // --- O += P·V : V b64 reads shared across q-groups; zero-padded halves ---
#pragma unroll
    for (int c = 0; c < 8; c++) {
      union { uint32_t w[4]; b8 v; } af0, af1;
      af0.w[0] = pf[0][c * 2]; af0.w[1] = pf[0][c * 2 + 1]; af0.w[2] = 0u; af0.w[3] = 0u;
      af1.w[0] = pf[1][c * 2]; af1.w[1] = pf[1][c * 2 + 1]; af1.w[2] = 0u; af1.w[3] = 0u;
#pragma unroll
      for (int dg = 0; dg < 4; dg++) {
        const uint2 vd = *(const uint2*)&Vt[(dg * 16 + l15) * 132 + c * 16 + quad * 4];
        union { uint32_t w[4]; b8 v; } vb;
        vb.w[0] = vd.x; vb.w[1] = vd.y; vb.w[2] = 0u; vb.w[3] = 0u;
        o[0][dg] = __builtin_amdgcn_mfma_f32_16x16x32_bf16(af0.v, vb.v, o[0][dg], 0, 0, 0);
        o[1][dg] = __builtin_amdgcn_mfma_f32_16x16x32_bf16(af1.v, vb.v, o[1][dg], 0, 0, 0);
      }
    }
    __syncthreads();   // before next tile overwrites Ks/Vt
  }

#pragma unroll
  for (int qg = 0; qg < 2; qg++) {
    float lr[4];
#pragma unroll
    for (int r = 0; r < 4; r++) lr[r] = __shfl(lrow[qg], quad * 4 + r, 64);
#pragma unroll
    for (int dg = 0; dg < 4; dg++)
#pragma unroll
      for (int r = 0; r < 4; r++) {
        const int gq = q0 + wave * 32 + qg * 16 + quad * 4 + r;
        y[(size_t)(bb * SEQ + gq) * EMB + h * 64 + dg * 16 + l15] = f2b(o[qg][dg][r] / lr[r]);
      }
  }
}

extern "C" void kernel_launch(void* const* d_in, const int* in_sizes, int n_in,
                              void* d_out, int out_size, void* d_ws, size_t ws_size,
                              hipStream_t stream) {
  const float* x = (const float*)d_in[0];
  const float* Wq = (const float*)d_in[1];
  const float* bq = (const float*)d_in[2];
  const float* Wk = (const float*)d_in[3];
  const float* bk = (const float*)d_in[4];
  const float* Wv = (const float*)d_in[5];
  const float* bv = (const float*)d_in[6];
  const float* Wo = (const float*)d_in[7];
  const float* bo = (const float*)d_in[8];
  const float* g1 = (const float*)d_in[9];
  const float* be1 = (const float*)d_in[10];
  const float* g2 = (const float*)d_in[11];
  const float* be2 = (const float*)d_in[12];
  const float* W1 = (const float*)d_in[13];
  const float* b1 = (const float*)d_in[14];
  const float* W2 = (const float*)d_in[15];
  const float* b2 = (const float*)d_in[16];
  float* out = (float*)d_out;

  char* ws = (char*)d_ws;
  const size_t MB = 1024ull * 1024ull;
  us* WqkvT = (us*)(ws + 0);          // [3072][1024] bf16
  us* WoT   = (us*)(ws + 6 * MB);     // [1024][1024]
  us* W1T   = (us*)(ws + 8 * MB);     // [4096][1024]
  us* W2T   = (us*)(ws + 16 * MB);    // [1024][4096]
  us* hbuf  = (us*)(ws + 24 * MB);    // [8192][1024] bf16 (LN1 out)
  us* qkvb  = (us*)(ws + 40 * MB);    // [8192][3072] bf16
  us* ybuf  = (us*)(ws + 88 * MB);    // [8192][1024] bf16
  float* x1 = (float*)(ws + 104 * MB);// [8192][1024] f32
  us* h2    = (us*)(ws + 136 * MB);   // [8192][1024] bf16
  us* ff1   = (us*)(ws + 24 * MB);    // [8192][4096] bf16 (reuses h/qkv region)
  float* bqkv = (float*)(ws + 152 * MB); // [3072] f32

  transpose_cast<<<dim3(32, 32), 256, 0, stream>>>(Wq, WqkvT, 1024, 1024);
  transpose_cast<<<dim3(32, 32), 256, 0, stream>>>(Wk, WqkvT + 1024 * 1024, 1024, 1024);
  transpose_cast<<<dim3(32, 32), 256, 0, stream>>>(Wv, WqkvT + 2 * 1024 * 1024, 1024, 1024);
  transpose_cast<<<dim3(32, 32), 256, 0, stream>>>(Wo, WoT, 1024, 1024);
  transpose_cast<<<dim3(128, 32), 256, 0, stream>>>(W1, W1T, 1024, 4096);
  transpose_cast<<<dim3(32, 128), 256, 0, stream>>>(W2, W2T, 4096, 1024);
  pack_bias<<<12, 256, 0, stream>>>(bq, bk, bv, bqkv);

  ln_kernel<<<NTOK, 256, 0, stream>>>(x, g1, be1, hbuf);
  gemm_bt<<<dim3(64, 24), 256, 0, stream>>>(hbuf, WqkvT, bqkv, nullptr, nullptr, qkvb,
                                            NTOK, 3072, 1024, 0);
  attn<<<1024, 256, 0, stream>>>(qkvb, ybuf);
  gemm_bt<<<dim3(64, 8), 256, 0, stream>>>(ybuf, WoT, bo, x, x1, nullptr,
                                           NTOK, 1024, 1024, 0);
  ln_kernel<<<NTOK, 256, 0, stream>>>(x1, g2, be2, h2);
  gemm_bt<<<dim3(64, 32), 256, 0, stream>>>(h2, W1T, b1, nullptr, nullptr, ff1,
                                            NTOK, 4096, 1024, 1);
  gemm_bt<<<dim3(64, 8), 256, 0, stream>>>(ff1, W2T, b2, x1, out, nullptr,
                                           NTOK, 1024, 4096, 0);
}